// Round 6
// baseline (728.903 us; speedup 1.0000x reference)
//
#include <hip/hip_runtime.h>
#include <math.h>

#define BN 1024
#define SN 64
#define DN 256
#define CHN 1024
#define GRP 16

__device__ __forceinline__ float gelu_exact(float x) {
    return 0.5f * x * (1.0f + erff(x * 0.70710678118654752440f));
}

// K1: scene logits + log_softmax + argmax + pose-bias init + scene binning.
// One block per sample b, 256 thr = 4 waves. (unchanged, proven)
__global__ __launch_bounds__(256, 4) void k_scene(
    const float* __restrict__ dt, const float* __restrict__ dr,
    const float* __restrict__ Wsc, const float* __restrict__ bsc,
    const float* __restrict__ bt_o, const float* __restrict__ br_o,
    float* __restrict__ out_logd, float* __restrict__ pose,
    int* __restrict__ counts, int* __restrict__ lists)
{
    int b = blockIdx.x;
    int tid = threadIdx.x;
    int lane = tid & 63;
    int wave = tid >> 6;
    __shared__ float part[SN][65];   // +1 pad: reduction read is 2-way (free)
    __shared__ float logits[SN];

    float4 wt = *(const float4*)&Wsc[4 * lane];
    float4 wr = *(const float4*)&Wsc[DN + 4 * lane];
    const float* pt = dt + (size_t)b * SN * DN + 4 * lane;
    const float* pr = dr + (size_t)b * SN * DN + 4 * lane;
    float bias0 = bsc[0];

    float p[16];
    #pragma unroll 8
    for (int k = 0; k < 16; k++) {
        int s = wave * 16 + k;          // each wave streams a contiguous 16KB chunk
        float4 t4 = *(const float4*)&pt[s * DN];
        float4 r4 = *(const float4*)&pr[s * DN];
        p[k] = t4.x * wt.x + t4.y * wt.y + t4.z * wt.z + t4.w * wt.w
             + r4.x * wr.x + r4.y * wr.y + r4.z * wr.z + r4.w * wr.w;
    }
    #pragma unroll
    for (int k = 0; k < 16; k++) part[wave * 16 + k][lane] = p[k];
    __syncthreads();

    {
        int s = tid >> 2, q = tid & 3;
        float sum = 0.f;
        #pragma unroll
        for (int j = 0; j < 16; j++) sum += part[s][q * 16 + j];
        sum += __shfl_xor(sum, 1);
        sum += __shfl_xor(sum, 2);
        if (q == 0) logits[s] = sum + bias0;
    }
    __syncthreads();

    if (wave == 0) {
        float l = logits[lane];
        float m = l; int idx = lane;
        #pragma unroll
        for (int off = 32; off >= 1; off >>= 1) {
            float om = __shfl_xor(m, off);
            int oidx = __shfl_xor(idx, off);
            if (om > m || (om == m && oidx < idx)) { m = om; idx = oidx; }
        }
        float e = expf(l - m);
        float ssum = e;
        #pragma unroll
        for (int off = 32; off >= 1; off >>= 1) ssum += __shfl_xor(ssum, off);
        float logZ = m + logf(ssum);
        out_logd[b * SN + lane] = l - logZ;
        // fused prep: bin this sample + write pose output biases
        if (lane == 0) {
            int pos = atomicAdd(&counts[idx], 1);
            lists[idx * BN + pos] = b;
        }
        if (lane < 7)
            pose[b * 7 + lane] = (lane < 3) ? bt_o[idx * 3 + lane]
                                            : br_o[idx * 4 + (lane - 3)];
    }
}

// K2 v5: v4 + deep weight prefetch (the ONE changed variable).
// Evidence: v1/v3/v4 all pinned at 93us with VALUBusy 19-41%, occ 20-38%,
// 0 bank conflicts, HBM 11% -> waves are ~88% stalled on vmcnt with only
// ~4KB/wave in flight (prefetch depth 1). v5 rotates a w[4][4] register
// buffer, keeping 3 steps (12 loads, 12KB/wave) in flight; no barriers in
// the loop so the compiler can emit counted vmcnt(N) for register consumers.
// All acc[]/w[][] indices are compile-time constants -> VGPRs, not scratch.
__global__ __launch_bounds__(256, 2) void k_expert(
    const float* __restrict__ dt, const float* __restrict__ dr,
    const float* __restrict__ Wt_h, const float* __restrict__ bt_h, const float* __restrict__ Wt_o,
    const float* __restrict__ Wr_h, const float* __restrict__ br_h, const float* __restrict__ Wr_o,
    const int* __restrict__ counts, const int* __restrict__ lists,
    float* __restrict__ pose)
{
    __shared__ float g[GRP][DN];      // 16 KB gathered descriptors
    __shared__ float comb[GRP][DN];   // 16 KB combine buffer
    __shared__ int pref[SN + 1];
    __shared__ int bl[GRP];
    int tid = threadIdx.x;
    int lane = tid & 63;
    int wv = tid >> 6;

    // group-count prefix scan (wave 0)
    if (tid < 64) {
        int c = counts[lane];
        int ng = (c + GRP - 1) >> 4;
        #pragma unroll
        for (int off = 1; off < 64; off <<= 1) {
            int v = __shfl_up(ng, off);
            if (lane >= off) ng += v;
        }
        pref[lane + 1] = ng;
        if (lane == 0) pref[0] = 0;
    }
    __syncthreads();

    int q = blockIdx.x;
    if (q >= pref[SN] * 8) return;   // uniform exit

    int s = 0;
    while (pref[s + 1] * 8 <= q) s++;
    int r = q - pref[s] * 8;
    int grp = r >> 3;                // group of up to 16 samples
    int z = (r >> 2) & 1;            // head type (t / rot)
    int chunk = r & 3;               // 256-col chunk of CH

    int cnt = counts[s];
    int base = grp * GRP;
    int n = min(GRP, cnt - base);

    const float* Wh; const float* bh; const float* Wo; const float* descs; int no, ob;
    if (z == 0) {
        Wh = Wt_h + (size_t)s * DN * CHN; bh = bt_h + s * CHN;
        Wo = Wt_o + (size_t)s * CHN * 3;  descs = dt; no = 3; ob = 0;
    } else {
        Wh = Wr_h + (size_t)s * DN * CHN; bh = br_h + s * CHN;
        Wo = Wr_o + (size_t)s * CHN * 4;  descs = dr; no = 4; ob = 3;
    }

    // gather: 16 rows x 256 floats, one row per 256-thread pass (coalesced)
    #pragma unroll 4
    for (int i = 0; i < GRP; i++) {
        int bi = 0; float v = 0.f;
        if (i < n) {
            bi = lists[s * BN + base + i];
            v = descs[(size_t)bi * SN * DN + s * DN + tid];
        }
        g[i][tid] = v;
        if (tid == 0) bl[i] = bi;
    }
    __syncthreads();

    int d0 = wv << 6;                // wave owns rows d0..d0+63
    int h0 = (chunk << 8) + lane * 4; // 4 adjacent hidden cols
    const float* wp = Wh + (size_t)d0 * CHN + h0;

    float4 acc[GRP];
    #pragma unroll
    for (int i = 0; i < GRP; i++) acc[i] = make_float4(0.f, 0.f, 0.f, 0.f);

    // deep-pipelined main loop: 16 steps of 4 rows; rotating 4-slot weight
    // buffer, 3 steps (12 dwordx4 = 12KB/wave) in flight ahead of compute
    float4 w[4][4];
    #pragma unroll
    for (int pf = 0; pf < 3; pf++) {
        #pragma unroll
        for (int rr = 0; rr < 4; rr++)
            w[pf][rr] = *(const float4*)&wp[(size_t)(pf * 4 + rr) * CHN];
    }
    #pragma unroll
    for (int st = 0; st < 16; st++) {
        int slot = st & 3;
        if (st + 3 < 16) {           // compile-time per unrolled iteration
            int nslot = (st + 3) & 3;
            int db = (st + 3) * 4;
            #pragma unroll
            for (int rr = 0; rr < 4; rr++)
                w[nslot][rr] = *(const float4*)&wp[(size_t)(db + rr) * CHN];
        }
        int db = st * 4;
        #pragma unroll
        for (int i = 0; i < GRP; i++) {
            float4 gv = *(const float4*)&g[i][d0 + db];  // wave-uniform broadcast
            acc[i].x += gv.x * w[slot][0].x + gv.y * w[slot][1].x
                      + gv.z * w[slot][2].x + gv.w * w[slot][3].x;
            acc[i].y += gv.x * w[slot][0].y + gv.y * w[slot][1].y
                      + gv.z * w[slot][2].y + gv.w * w[slot][3].y;
            acc[i].z += gv.x * w[slot][0].z + gv.y * w[slot][1].z
                      + gv.z * w[slot][2].z + gv.w * w[slot][3].z;
            acc[i].w += gv.x * w[slot][0].w + gv.y * w[slot][1].w
                      + gv.z * w[slot][2].w + gv.w * w[slot][3].w;
        }
    }

    // combine quarters: wv2->g, wv3->comb; wv0+=g, wv1+=comb; wv1->g; wv0+=g
    __syncthreads();                 // all waves done reading g
    if (wv == 2) {
        #pragma unroll
        for (int i = 0; i < GRP; i++) *(float4*)&g[i][lane * 4] = acc[i];
    } else if (wv == 3) {
        #pragma unroll
        for (int i = 0; i < GRP; i++) *(float4*)&comb[i][lane * 4] = acc[i];
    }
    __syncthreads();
    if (wv == 0) {
        #pragma unroll
        for (int i = 0; i < GRP; i++) {
            float4 v = *(const float4*)&g[i][lane * 4];
            acc[i].x += v.x; acc[i].y += v.y; acc[i].z += v.z; acc[i].w += v.w;
        }
    } else if (wv == 1) {
        #pragma unroll
        for (int i = 0; i < GRP; i++) {
            float4 v = *(const float4*)&comb[i][lane * 4];
            acc[i].x += v.x; acc[i].y += v.y; acc[i].z += v.z; acc[i].w += v.w;
        }
    }
    __syncthreads();
    if (wv == 1) {
        #pragma unroll
        for (int i = 0; i < GRP; i++) *(float4*)&g[i][lane * 4] = acc[i];
    }
    __syncthreads();
    if (wv != 0) return;             // all barriers passed; wave 0 finishes
    #pragma unroll
    for (int i = 0; i < GRP; i++) {
        float4 v = *(const float4*)&g[i][lane * 4];
        acc[i].x += v.x; acc[i].y += v.y; acc[i].z += v.z; acc[i].w += v.w;
    }

    float4 hb4 = *(const float4*)&bh[h0];
    float wo[4][4];                  // wo[o][c] = Wo[(h0+c)*no + o]
    #pragma unroll
    for (int c = 0; c < 4; c++)
        #pragma unroll
        for (int o = 0; o < 4; o++)
            wo[o][c] = (o < no) ? Wo[(size_t)(h0 + c) * no + o] : 0.f;

    #pragma unroll
    for (int i = 0; i < GRP; i++) {
        if (i < n) {
            float hx = gelu_exact(acc[i].x + hb4.x);
            float hy = gelu_exact(acc[i].y + hb4.y);
            float hz = gelu_exact(acc[i].z + hb4.z);
            float hw = gelu_exact(acc[i].w + hb4.w);
            #pragma unroll
            for (int o = 0; o < 4; o++) {
                if (o < no) {
                    float p = hx * wo[o][0] + hy * wo[o][1]
                            + hz * wo[o][2] + hw * wo[o][3];
                    #pragma unroll
                    for (int off = 32; off >= 1; off >>= 1) p += __shfl_down(p, off);
                    if (lane == 0) atomicAdd(&pose[bl[i] * 7 + ob + o], p);
                }
            }
        }
    }
}

extern "C" void kernel_launch(void* const* d_in, const int* in_sizes, int n_in,
                              void* d_out, int out_size, void* d_ws, size_t ws_size,
                              hipStream_t stream) {
    const float* dt    = (const float*)d_in[0];
    const float* dr    = (const float*)d_in[1];
    const float* Wsc   = (const float*)d_in[2];
    const float* bsc   = (const float*)d_in[3];
    const float* Wt_h  = (const float*)d_in[4];
    const float* bt_h  = (const float*)d_in[5];
    const float* Wt_o  = (const float*)d_in[6];
    const float* bt_o  = (const float*)d_in[7];
    const float* Wr_h  = (const float*)d_in[8];
    const float* br_h  = (const float*)d_in[9];
    const float* Wr_o  = (const float*)d_in[10];
    const float* br_o  = (const float*)d_in[11];

    float* pose = (float*)d_out;                    // [B,7]
    float* logd = (float*)d_out + BN * 7;           // [B,S]

    int* counts  = (int*)((char*)d_ws + 4096);              // 256 B
    int* lists   = (int*)((char*)d_ws + 8192);              // 256 KB

    hipMemsetAsync(counts, 0, SN * sizeof(int), stream);

    k_scene<<<BN, 256, 0, stream>>>(dt, dr, Wsc, bsc, bt_o, br_o,
                                    logd, pose, counts, lists);
    // max groups = sum ceil(cnt/16) <= (1024 + 64*15)/16 = 124; 124*8 = 992
    k_expert<<<992, 256, 0, stream>>>(
        dt, dr, Wt_h, bt_h, Wt_o, Wr_h, br_h, Wr_o, counts, lists, pose);
}

// Round 7
// 290.795 us; speedup vs baseline: 2.5066x; 2.5066x over previous
//
#include <hip/hip_runtime.h>
#include <math.h>

#define BN 1024
#define SN 64
#define DN 256
#define CHN 1024
#define GRP 16

#define LDS_AS __attribute__((address_space(3)))
#define GLB_AS __attribute__((address_space(1)))

__device__ __forceinline__ float gelu_exact(float x) {
    return 0.5f * x * (1.0f + erff(x * 0.70710678118654752440f));
}

// async DMA of one 1KB row (64 lanes x 16B) global -> LDS.
// LDS dest is wave-uniform base; HW adds lane*16. Global src is per-lane.
__device__ __forceinline__ void stage_row(const float* gsrc_lane, float* lds_row) {
    __builtin_amdgcn_global_load_lds((const GLB_AS void*)gsrc_lane,
                                     (LDS_AS void*)lds_row, 16, 0, 0);
}

// K1: scene logits + log_softmax + argmax + pose-bias init + scene binning.
// One block per sample b, 256 thr = 4 waves. (unchanged, proven)
__global__ __launch_bounds__(256, 4) void k_scene(
    const float* __restrict__ dt, const float* __restrict__ dr,
    const float* __restrict__ Wsc, const float* __restrict__ bsc,
    const float* __restrict__ bt_o, const float* __restrict__ br_o,
    float* __restrict__ out_logd, float* __restrict__ pose,
    int* __restrict__ counts, int* __restrict__ lists)
{
    int b = blockIdx.x;
    int tid = threadIdx.x;
    int lane = tid & 63;
    int wave = tid >> 6;
    __shared__ float part[SN][65];   // +1 pad: reduction read is 2-way (free)
    __shared__ float logits[SN];

    float4 wt = *(const float4*)&Wsc[4 * lane];
    float4 wr = *(const float4*)&Wsc[DN + 4 * lane];
    const float* pt = dt + (size_t)b * SN * DN + 4 * lane;
    const float* pr = dr + (size_t)b * SN * DN + 4 * lane;
    float bias0 = bsc[0];

    float p[16];
    #pragma unroll 8
    for (int k = 0; k < 16; k++) {
        int s = wave * 16 + k;          // each wave streams a contiguous 16KB chunk
        float4 t4 = *(const float4*)&pt[s * DN];
        float4 r4 = *(const float4*)&pr[s * DN];
        p[k] = t4.x * wt.x + t4.y * wt.y + t4.z * wt.z + t4.w * wt.w
             + r4.x * wr.x + r4.y * wr.y + r4.z * wr.z + r4.w * wr.w;
    }
    #pragma unroll
    for (int k = 0; k < 16; k++) part[wave * 16 + k][lane] = p[k];
    __syncthreads();

    {
        int s = tid >> 2, q = tid & 3;
        float sum = 0.f;
        #pragma unroll
        for (int j = 0; j < 16; j++) sum += part[s][q * 16 + j];
        sum += __shfl_xor(sum, 1);
        sum += __shfl_xor(sum, 2);
        if (q == 0) logits[s] = sum + bias0;
    }
    __syncthreads();

    if (wave == 0) {
        float l = logits[lane];
        float m = l; int idx = lane;
        #pragma unroll
        for (int off = 32; off >= 1; off >>= 1) {
            float om = __shfl_xor(m, off);
            int oidx = __shfl_xor(idx, off);
            if (om > m || (om == m && oidx < idx)) { m = om; idx = oidx; }
        }
        float e = expf(l - m);
        float ssum = e;
        #pragma unroll
        for (int off = 32; off >= 1; off >>= 1) ssum += __shfl_xor(ssum, off);
        float logZ = m + logf(ssum);
        out_logd[b * SN + lane] = l - logZ;
        // fused prep: bin this sample + write pose output biases
        if (lane == 0) {
            int pos = atomicAdd(&counts[idx], 1);
            lists[idx * BN + pos] = b;
        }
        if (lane < 7)
            pose[b * 7 + lane] = (lane < 3) ? bt_o[idx * 3 + lane]
                                            : br_o[idx * 4 + (lane - 3)];
    }
}

// K2 v6: global_load_lds double-buffered weight staging (2-phase pipeline).
// v5 post-mortem: register prefetch buffer went to SCRATCH (WRITE_SIZE 798MB)
// -> in-flight bytes must live in LDS, not VGPRs. The DMA costs no VGPRs;
// STAGE(t+1) is issued BEFORE COMPUTE(t), so HBM/L3 latency hides under the
// ~2000-cyc compute phase; __syncthreads' implicit vmcnt(0) drain gives
// correctness (the loads had a full phase to land).
//  - no row-split any more: weights in LDS are shared by all 4 waves; each
//    wave owns 4 SAMPLES x all 256 rows -> no combine phase, acc = 16 VGPR.
//  - weight reads: contiguous wave-wide ds_read_b128 (1KB/row, standard).
//  - g broadcasts: wave-uniform address (conflict-free broadcast).
//  - stage of tile 0 overlaps the descriptor gather.
__global__ __launch_bounds__(256, 4) void k_expert(
    const float* __restrict__ dt, const float* __restrict__ dr,
    const float* __restrict__ Wt_h, const float* __restrict__ bt_h, const float* __restrict__ Wt_o,
    const float* __restrict__ Wr_h, const float* __restrict__ br_h, const float* __restrict__ Wr_o,
    const int* __restrict__ counts, const int* __restrict__ lists,
    float* __restrict__ pose)
{
    __shared__ float g[GRP][DN];        // 16 KB gathered descriptors
    __shared__ float wbuf[2][16][DN];   // 32 KB double-buffered weight tiles
    __shared__ int pref[SN + 1];
    __shared__ int bl[GRP];
    int tid = threadIdx.x;
    int lane = tid & 63;
    int wv = tid >> 6;

    // group-count prefix scan (wave 0)
    if (tid < 64) {
        int c = counts[lane];
        int ng = (c + GRP - 1) >> 4;
        #pragma unroll
        for (int off = 1; off < 64; off <<= 1) {
            int v = __shfl_up(ng, off);
            if (lane >= off) ng += v;
        }
        pref[lane + 1] = ng;
        if (lane == 0) pref[0] = 0;
    }
    __syncthreads();

    int q = blockIdx.x;
    if (q >= pref[SN] * 8) return;   // uniform exit

    int s = 0;
    while (pref[s + 1] * 8 <= q) s++;
    int r = q - pref[s] * 8;
    int grp = r >> 3;                // group of up to 16 samples
    int z = (r >> 2) & 1;            // head type (t / rot)
    int chunk = r & 3;               // 256-col chunk of CH

    int cnt = counts[s];
    int base = grp * GRP;
    int n = min(GRP, cnt - base);

    const float* Wh; const float* bh; const float* Wo; const float* descs; int no, ob;
    if (z == 0) {
        Wh = Wt_h + (size_t)s * DN * CHN; bh = bt_h + s * CHN;
        Wo = Wt_o + (size_t)s * CHN * 3;  descs = dt; no = 3; ob = 0;
    } else {
        Wh = Wr_h + (size_t)s * DN * CHN; bh = br_h + s * CHN;
        Wo = Wr_o + (size_t)s * CHN * 4;  descs = dr; no = 4; ob = 3;
    }

    // per-lane base of the weight column slice this block streams
    const float* wcol = Wh + (chunk << 8) + lane * 4;

    // prologue: stage tile 0 into wbuf[0] (DMA overlaps the gather below);
    // wave wv stages rows wv*4 .. wv*4+3
    #pragma unroll
    for (int k = 0; k < 4; k++) {
        int rr = wv * 4 + k;
        stage_row(wcol + (size_t)rr * CHN, &wbuf[0][rr][0]);
    }

    // gather: 16 rows x 256 floats, one row per 256-thread pass (coalesced)
    #pragma unroll 4
    for (int i = 0; i < GRP; i++) {
        int bi = 0; float v = 0.f;
        if (i < n) {
            bi = lists[s * BN + base + i];
            v = descs[(size_t)bi * SN * DN + s * DN + tid];
        }
        g[i][tid] = v;
        if (tid == 0) bl[i] = bi;
    }
    __syncthreads();                 // gather done + tile0 DMA drained

    int lane4 = lane * 4;            // this thread's 4 cols within the chunk
    int i0 = wv * 4;                 // this wave's 4 samples

    float4 acc[4];
    #pragma unroll
    for (int ii = 0; ii < 4; ii++) acc[ii] = make_float4(0.f, 0.f, 0.f, 0.f);

    // 16 tiles of 16 rows; 2-phase: stage next tile, compute current, barrier
    #pragma unroll 2
    for (int t = 0; t < 16; t++) {
        int cur = t & 1;
        if (t < 15) {                // issue next tile's DMA first
            #pragma unroll
            for (int k = 0; k < 4; k++) {
                int rr = wv * 4 + k;
                stage_row(wcol + (size_t)((t + 1) * 16 + rr) * CHN,
                          &wbuf[cur ^ 1][rr][0]);
            }
        }
        #pragma unroll
        for (int rg = 0; rg < 4; rg++) {
            float4 w0 = *(const float4*)&wbuf[cur][rg * 4 + 0][lane4];
            float4 w1 = *(const float4*)&wbuf[cur][rg * 4 + 1][lane4];
            float4 w2 = *(const float4*)&wbuf[cur][rg * 4 + 2][lane4];
            float4 w3 = *(const float4*)&wbuf[cur][rg * 4 + 3][lane4];
            #pragma unroll
            for (int ii = 0; ii < 4; ii++) {
                float4 gv = *(const float4*)&g[i0 + ii][t * 16 + rg * 4];
                acc[ii].x += gv.x * w0.x + gv.y * w1.x + gv.z * w2.x + gv.w * w3.x;
                acc[ii].y += gv.x * w0.y + gv.y * w1.y + gv.z * w2.y + gv.w * w3.y;
                acc[ii].z += gv.x * w0.z + gv.y * w1.z + gv.z * w2.z + gv.w * w3.z;
                acc[ii].w += gv.x * w0.w + gv.y * w1.w + gv.z * w2.w + gv.w * w3.w;
            }
        }
        __syncthreads();             // waves done with wbuf[cur]; next DMA landed
    }

    // epilogue: each wave finishes its own 4 samples (full 256-col chunk is
    // within the wave: lane4 spans 0..1023 bytes of cols)
    int h0 = (chunk << 8) + lane4;
    float4 hb4 = *(const float4*)&bh[h0];
    float wo[4][4];                  // wo[o][c] = Wo[(h0+c)*no + o]
    #pragma unroll
    for (int c = 0; c < 4; c++)
        #pragma unroll
        for (int o = 0; o < 4; o++)
            wo[o][c] = (o < no) ? Wo[(size_t)(h0 + c) * no + o] : 0.f;

    #pragma unroll
    for (int ii = 0; ii < 4; ii++) {
        int si = i0 + ii;
        if (si < n) {
            float hx = gelu_exact(acc[ii].x + hb4.x);
            float hy = gelu_exact(acc[ii].y + hb4.y);
            float hz = gelu_exact(acc[ii].z + hb4.z);
            float hw = gelu_exact(acc[ii].w + hb4.w);
            #pragma unroll
            for (int o = 0; o < 4; o++) {
                if (o < no) {
                    float p = hx * wo[o][0] + hy * wo[o][1]
                            + hz * wo[o][2] + hw * wo[o][3];
                    #pragma unroll
                    for (int off = 32; off >= 1; off >>= 1) p += __shfl_down(p, off);
                    if (lane == 0) atomicAdd(&pose[bl[si] * 7 + ob + o], p);
                }
            }
        }
    }
}

extern "C" void kernel_launch(void* const* d_in, const int* in_sizes, int n_in,
                              void* d_out, int out_size, void* d_ws, size_t ws_size,
                              hipStream_t stream) {
    const float* dt    = (const float*)d_in[0];
    const float* dr    = (const float*)d_in[1];
    const float* Wsc   = (const float*)d_in[2];
    const float* bsc   = (const float*)d_in[3];
    const float* Wt_h  = (const float*)d_in[4];
    const float* bt_h  = (const float*)d_in[5];
    const float* Wt_o  = (const float*)d_in[6];
    const float* bt_o  = (const float*)d_in[7];
    const float* Wr_h  = (const float*)d_in[8];
    const float* br_h  = (const float*)d_in[9];
    const float* Wr_o  = (const float*)d_in[10];
    const float* br_o  = (const float*)d_in[11];

    float* pose = (float*)d_out;                    // [B,7]
    float* logd = (float*)d_out + BN * 7;           // [B,S]

    int* counts  = (int*)((char*)d_ws + 4096);              // 256 B
    int* lists   = (int*)((char*)d_ws + 8192);              // 256 KB

    hipMemsetAsync(counts, 0, SN * sizeof(int), stream);

    k_scene<<<BN, 256, 0, stream>>>(dt, dr, Wsc, bsc, bt_o, br_o,
                                    logd, pose, counts, lists);
    // max groups = sum ceil(cnt/16) <= (1024 + 64*15)/16 = 124; 124*8 = 992
    k_expert<<<992, 256, 0, stream>>>(
        dt, dr, Wt_h, bt_h, Wt_o, Wr_h, br_h, Wr_o, counts, lists, pose);
}